// Round 20
// baseline (715.663 us; speedup 1.0000x reference)
//
#include <hip/hip_runtime.h>

static constexpr int ND1=160, ND2=160, ND3=32;
static constexpr int SP  = ND1*ND2*ND3;        // 819200
static constexpr int CO  = 64;
static constexpr int OD1=80, OD2=80, OD3=32;
static constexpr int OSP = OD1*OD2*OD3;        // 204800
static constexpr int NSC = 64;

typedef __attribute__((ext_vector_type(8)))  short  short8;
typedef __attribute__((ext_vector_type(4)))  float  f32x4;
typedef __attribute__((ext_vector_type(16))) float  f32x16;

__device__ __forceinline__ float b2f_lo(unsigned u){ return __uint_as_float(u<<16); }
__device__ __forceinline__ float b2f_hi(unsigned u){ return __uint_as_float(u & 0xffff0000u); }
__device__ __forceinline__ unsigned short f2b(float f){
    unsigned u = __float_as_uint(f);
    u += 0x7fffu + ((u>>16)&1u);
    return (unsigned short)(u>>16);
}
__device__ __forceinline__ unsigned cvtpk(float lo, float hi){
    unsigned r;
    asm("v_cvt_pk_bf16_f32 %0, %1, %2" : "=v"(r) : "v"(lo), "v"(hi));
    return r;
}
__device__ __forceinline__ float lrelu(float x){ return fmaxf(x, 0.01f*x); }

// ---------------- mask dtype detection ----------------
__global__ void k_detect(const unsigned char* __restrict__ mb, int* __restrict__ flag)
{
    __shared__ int lf;
    if (threadIdx.x == 0) lf = 0;
    __syncthreads();
    int f = 0;
    for (int i = blockIdx.x*256 + threadIdx.x; i < SP; i += gridDim.x*256) {
        unsigned char b = mb[i];
        if (b > 1) f |= 4;
        if (b != 0 && (i & 3)) f |= 1;
    }
    if (f) atomicOr(&lf, f);
    __syncthreads();
    if (threadIdx.x == 0 && lf) atomicOr(flag, lf);
}

__global__ void k_mask(const void* __restrict__ mraw, const int* __restrict__ flag,
                       float* __restrict__ m, float* __restrict__ nactN)
{
    int i = blockIdx.x*256 + threadIdx.x;
    int f = *flag;
    float v;
    if (f & 4)      v = (reinterpret_cast<const float*>(mraw)[i] != 0.f) ? 1.f : 0.f;
    else if (f & 1) v = (reinterpret_cast<const unsigned char*>(mraw)[i] != 0) ? 1.f : 0.f;
    else            v = (reinterpret_cast<const int*>(mraw)[i] != 0) ? 1.f : 0.f;
    m[i] = v;
    float s = v;
    #pragma unroll
    for (int off = 32; off > 0; off >>= 1) s += __shfl_xor(s, off);
    __shared__ float wsum[4];
    if ((threadIdx.x & 63) == 0) wsum[threadIdx.x >> 6] = s;
    __syncthreads();
    if (threadIdx.x == 0) atomicAdd(&nactN[blockIdx.x & (NSC-1)], wsum[0]+wsum[1]+wsum[2]+wsum[3]);
}

// ---------------- BN finalize (2 stages/launch) ----------------
__global__ void k_finalize2(const float* __restrict__ SN0, const float* __restrict__ g0,
                            const float* __restrict__ b0, float* __restrict__ o0,
                            const float* __restrict__ SN1, const float* __restrict__ g1,
                            const float* __restrict__ b1, float* __restrict__ o1,
                            const float* __restrict__ nactN)
{
    const float* SN = blockIdx.x ? SN1 : SN0;
    const float* g  = blockIdx.x ? g1  : g0;
    const float* b  = blockIdx.x ? b1  : b0;
    float*       o  = blockIdx.x ? o1  : o0;
    int c = threadIdx.x;
    float s1 = 0.f, s2 = 0.f;
    #pragma unroll 4
    for (int k = 0; k < NSC; k++){
        s1 += SN[k*128 + c];
        s2 += SN[k*128 + 64 + c];
    }
    float nn = nactN[c];
    #pragma unroll
    for (int off = 32; off > 0; off >>= 1) nn += __shfl_xor(nn, off);
    float mean = s1 / nn;
    float var  = s2 / nn - mean*mean;
    float inv  = rsqrtf(var + 1e-5f);
    float sc   = inv * g[c];
    o[c]      = sc;
    o[64 + c] = b[c] - mean*sc;
}

// ---------------- merged weight pre-pack ----------------
// conv tensors: 32x32x16 A-frag layout  Wt[tap*NK16+k16][co64][16k]
// pool tensor:  legacy 16x16x32 layout  Wt[kc][co64][32k]
__global__ void k_wprep_all(const float* __restrict__ WA1, const float* __restrict__ WA2,
                            const float* __restrict__ WB1, const float* __restrict__ WB2,
                            const float* __restrict__ WP,
                            unsigned short* __restrict__ tA1, unsigned short* __restrict__ tA2,
                            unsigned short* __restrict__ tB1, unsigned short* __restrict__ tB2,
                            unsigned short* __restrict__ tP)
{
    int i = blockIdx.x*256 + threadIdx.x;
    if (i < 110592){
        const float* W; unsigned short* Wt; int CIN, base;
        if      (i < 18432)  { W=WA1; Wt=tA1; CIN=32; base=0; }
        else if (i < 55296)  { W=WA2; Wt=tA2; CIN=64; base=18432; }
        else if (i < 73728)  { W=WB1; Wt=tB1; CIN=32; base=55296; }
        else                 { W=WB2; Wt=tB2; CIN=64; base=73728; }
        int j = i - base;
        int k   = j & 15;
        int t   = j >> 4;
        int co  = t & 63;
        int kci = t >> 6;
        int nk16 = CIN >> 4;
        int tap = kci / nk16;
        int k16 = kci - tap*nk16;
        int ci  = k16*16 + k;
        Wt[j] = f2b(W[((size_t)co*CIN + ci)*9 + tap]);
    } else if (i < 221184){
        int j = i - 110592;
        int ksub = j & 31;
        int t = j >> 5;
        int co = t & 63;
        int kc = t >> 6;
        int tap = kc / 2;
        int ci  = (kc - tap*2)*32 + ksub;
        tP[j] = f2b(WP[((size_t)co*64 + ci)*27 + tap]);
    }
}

// ---------------- x prep (+ out_mask fold) ----------------
__global__ void k_prep_x(const float* __restrict__ x, const float* __restrict__ m,
                         unsigned short* __restrict__ xt, float* __restrict__ om)
{
    __shared__ float t[64][33];
    int sp0 = blockIdx.x*64;
    int tid = threadIdx.x;
    int c = tid>>6, s = tid&63;
    float mm = m[sp0+s];
    #pragma unroll
    for (int r=0;r<8;r++){
        int ci = c + r*4;
        t[s][ci] = x[(size_t)ci*SP + sp0 + s]*mm;
    }
    __syncthreads();
    int sp = tid>>2, c0 = (tid&3)*8;
    uint4 pk;
    pk.x = cvtpk(t[sp][c0+0], t[sp][c0+1]);
    pk.y = cvtpk(t[sp][c0+2], t[sp][c0+3]);
    pk.z = cvtpk(t[sp][c0+4], t[sp][c0+5]);
    pk.w = cvtpk(t[sp][c0+6], t[sp][c0+7]);
    *reinterpret_cast<uint4*>(xt + (size_t)(sp0+sp)*32 + c0) = pk;

    if (blockIdx.x < OSP/256){
        int i = blockIdx.x*256 + tid;
        int o3 = i & 31; int tt = i >> 5; int o2 = tt % OD2; int o1 = tt / OD2;
        float ssum = 0.f;
        for (int kd = 0; kd < 3; kd++) { int d1 = 2*o1 - 1 + kd; if ((unsigned)d1 >= ND1) continue;
          for (int kh = 0; kh < 3; kh++) { int d2 = 2*o2 - 1 + kh; if ((unsigned)d2 >= ND2) continue;
            for (int kw = 0; kw < 3; kw++) { int d3 = o3 - 1 + kw; if ((unsigned)d3 >= ND3) continue;
              ssum += m[(d1*ND2 + d2)*ND3 + d3];
            } } }
        om[i] = (ssum > 0.f) ? 1.f : 0.f;
    }
}

// ---------------- res_B combine ----------------
__global__ void k_resB(const unsigned short* __restrict__ hA, const unsigned short* __restrict__ hB,
                       const float* __restrict__ sA, const float* __restrict__ sB,
                       const float* __restrict__ m,
                       unsigned short* __restrict__ rbt, float* __restrict__ resf)
{
    __shared__ float t[64][65];
    __shared__ float ss[256];
    int tid = threadIdx.x;
    if (tid < 128){ ss[tid] = sA[tid]; ss[128+tid] = sB[tid]; }
    __syncthreads();
    int sp0 = blockIdx.x*64;
    int sp = tid>>2, c0 = (tid&3)*16;
    float mm = m[sp0+sp];
    const size_t base = (size_t)(sp0+sp)*64 + c0;
    uint4 a0 = *reinterpret_cast<const uint4*>(hA + base);
    uint4 a1 = *reinterpret_cast<const uint4*>(hA + base + 8);
    uint4 b0 = *reinterpret_cast<const uint4*>(hB + base);
    uint4 b1 = *reinterpret_cast<const uint4*>(hB + base + 8);
    unsigned pa4[8] = {a0.x,a0.y,a0.z,a0.w,a1.x,a1.y,a1.z,a1.w};
    unsigned pb4[8] = {b0.x,b0.y,b0.z,b0.w,b1.x,b1.y,b1.z,b1.w};
    float vv[16];
    #pragma unroll
    for (int q=0;q<8;q++){
        int ci = c0+q*2;
        float va0 = b2f_lo(pa4[q]), va1 = b2f_hi(pa4[q]);
        float vb0 = b2f_lo(pb4[q]), vb1 = b2f_hi(pb4[q]);
        float v0 = (va0*ss[ci]   + ss[64+ci]   + vb0*ss[128+ci]   + ss[192+ci])*mm;
        float v1 = (va1*ss[ci+1] + ss[64+ci+1] + vb1*ss[128+ci+1] + ss[192+ci+1])*mm;
        t[sp][ci] = v0; t[sp][ci+1] = v1;
        vv[q*2] = v0; vv[q*2+1] = v1;
    }
    uint4 p0, p1;
    p0.x = cvtpk(vv[0],vv[1]);   p0.y = cvtpk(vv[2],vv[3]);
    p0.z = cvtpk(vv[4],vv[5]);   p0.w = cvtpk(vv[6],vv[7]);
    p1.x = cvtpk(vv[8],vv[9]);   p1.y = cvtpk(vv[10],vv[11]);
    p1.z = cvtpk(vv[12],vv[13]); p1.w = cvtpk(vv[14],vv[15]);
    *reinterpret_cast<uint4*>(rbt + base)     = p0;
    *reinterpret_cast<uint4*>(rbt + base + 8) = p1;
    __syncthreads();
    int ci = tid>>2, s0 = (tid&3)*16;
    #pragma unroll
    for (int kq=0;kq<4;kq++){
        float4 ov;
        ov.x = t[s0+4*kq+0][ci]; ov.y = t[s0+4*kq+1][ci];
        ov.z = t[s0+4*kq+2][ci]; ov.w = t[s0+4*kq+3][ci];
        *reinterpret_cast<float4*>(resf + (size_t)ci*SP + sp0 + s0 + 4*kq) = ov;
    }
}

// ---------------- dual MFMA conv: 32x32x16 MFMA (half the ds_reads & MFMA count) ----------------
// Wave w: rows 2w, 2w+1; both co-tiles (ct 0,1). acc[2ct][2row] f32x16 = 64 regs.
// B-frag: lane = o3 (l&31), k-half = l>>5; weights: lane = co row, k-half = l>>5.
template<int CIN, bool HASAFF, int KA, int KB>
__launch_bounds__(256, 3)
__global__ void mconv_dual(const unsigned short* __restrict__ inA, const unsigned short* __restrict__ WtA,
                           const float* __restrict__ scshA, unsigned short* __restrict__ outA,
                           float* __restrict__ statsA,
                           const unsigned short* __restrict__ inB, const unsigned short* __restrict__ WtB,
                           const float* __restrict__ scshB, unsigned short* __restrict__ outB2,
                           float* __restrict__ statsB,
                           const float* __restrict__ mstage, const float* __restrict__ mout)
{
    constexpr int NK16 = CIN/16;
    constexpr int NR   = 10;
    constexpr int ROWB = 34*CIN*2;
    constexpr int SWZ  = (CIN==64) ? 7 : 3;
    constexpr int OBST = 144;
    constexpr int LDSZ = (NR*ROWB > 256*OBST) ? NR*ROWB : 256*OBST;
    __shared__ __align__(16) char lds[LDSZ];
    __shared__ float sst[128];

    const int tid = threadIdx.x;
    const int w = tid>>6, l = tid&63;
    const int cl = l & 31, hf = l >> 5;

    const int bid  = blockIdx.x;
    const int hb   = (bid >= 3200) ? 1 : 0;
    const int b2   = bid - hb*3200;
    const int gi   = (b2&7)*400 + (b2>>3);
    const int kind = hb ? KB : KA;
    const unsigned short* in  = hb ? inB   : inA;
    const unsigned short* Wt  = hb ? WtB   : WtA;
    const float*        scsh  = hb ? scshB : scshA;
    unsigned short*     outb  = hb ? outB2 : outA;
    float*             statsN = hb ? statsB : statsA;

    int z  = gi % 160;
    int r0 = (gi / 160)*8;

    if (tid < 128) sst[tid] = 0.f;

    const int sd3 = tid>>3;
    const int k0  = (tid&7)*(CIN/8);

    float sc[8], sh[8];
    if (HASAFF){
        #pragma unroll
        for (int j=0;j<8;j++){ sc[j]=scsh[k0+j]; sh[j]=scsh[64+k0+j]; }
    }

    // border zeros (slots 0 and 33), XOR-swizzled (proven layout)
    for (int i = tid; i < NR*2*(CIN/8); i += 256){
        int per = CIN/8;
        int rr = i / (2*per);
        int rem = i - rr*2*per;
        int slot = (rem >= per) ? 33 : 0;
        int kc16 = (rem >= per) ? (rem - per) : rem;
        int dst = rr*ROWB + slot*CIN*2 + kc16*16;
        dst ^= ((slot&SWZ)<<4);
        *reinterpret_cast<uint4*>(lds + dst) = make_uint4(0,0,0,0);
    }

    // stage full-CIN rows, batched, slot-XOR swizzled (proven)
    if (CIN==64){
        uint4 v[NR]; float mmr[NR];
        #pragma unroll
        for (int rr=0; rr<NR; rr++){
            int rw = r0 - 1 + rr;
            v[rr] = make_uint4(0,0,0,0); mmr[rr] = 0.f;
            if ((unsigned)rw < 160u){
                int vox = (kind==0) ? ((rw*ND2 + z)*ND3 + sd3)
                                    : ((z*ND2 + rw)*ND3 + sd3);
                v[rr] = *reinterpret_cast<const uint4*>(in + (size_t)vox*CIN + k0);
                if (HASAFF) mmr[rr] = mstage[vox];
            }
        }
        #pragma unroll
        for (int rr=0; rr<NR; rr++){
            uint4 vv = v[rr];
            if (HASAFF){
                float mm = mmr[rr];
                float q0 = (b2f_lo(vv.x)*sc[0]+sh[0])*mm;
                float q1 = (b2f_hi(vv.x)*sc[1]+sh[1])*mm;
                float q2 = (b2f_lo(vv.y)*sc[2]+sh[2])*mm;
                float q3 = (b2f_hi(vv.y)*sc[3]+sh[3])*mm;
                float q4 = (b2f_lo(vv.z)*sc[4]+sh[4])*mm;
                float q5 = (b2f_hi(vv.z)*sc[5]+sh[5])*mm;
                float q6 = (b2f_lo(vv.w)*sc[6]+sh[6])*mm;
                float q7 = (b2f_hi(vv.w)*sc[7]+sh[7])*mm;
                vv.x = cvtpk(q0,q1); vv.y = cvtpk(q2,q3);
                vv.z = cvtpk(q4,q5); vv.w = cvtpk(q6,q7);
            }
            int dst = (rr*ROWB + (((sd3+1)*CIN + k0)*2)) ^ (((sd3+1)&SWZ)<<4);
            *reinterpret_cast<uint4*>(lds + dst) = vv;
        }
    } else {
        uint2 v[NR];
        #pragma unroll
        for (int rr=0; rr<NR; rr++){
            int rw = r0 - 1 + rr;
            v[rr] = make_uint2(0,0);
            if ((unsigned)rw < 160u){
                int vox = (kind==0) ? ((rw*ND2 + z)*ND3 + sd3)
                                    : ((z*ND2 + rw)*ND3 + sd3);
                v[rr] = *reinterpret_cast<const uint2*>(in + (size_t)vox*CIN + k0);
            }
        }
        #pragma unroll
        for (int rr=0; rr<NR; rr++){
            int dst = (rr*ROWB + (((sd3+1)*CIN + k0)*2)) ^ (((sd3+1)&SWZ)<<4);
            *reinterpret_cast<uint2*>(lds + dst) = v[rr];
        }
    }

    // per-row read bases: rows 2w+tr; lane covers o3 = cl, k-half hf
    int tb0[2];
    #pragma unroll
    for (int tr=0;tr<2;tr++)
        tb0[tr] = (2*w+tr)*ROWB + cl*CIN*2 + hf*16;

    __syncthreads();

    f32x16 acc[2][2];
    #pragma unroll
    for (int ct=0;ct<2;ct++)
        #pragma unroll
        for (int tr=0;tr<2;tr++)
            #pragma unroll
            for (int q=0;q<16;q++) acc[ct][tr][q] = 0.f;

    const unsigned short* wb = Wt + cl*16 + hf*8;

    #pragma unroll 1
    for (int k16=0; k16<NK16; k16++){
        short8 pa[9][2];
        #pragma unroll
        for (int tap=0; tap<9; tap++){
            const int kci = tap*NK16 + k16;
            pa[tap][0] = *reinterpret_cast<const short8*>(wb + (size_t)kci*1024);
            pa[tap][1] = *reinterpret_cast<const short8*>(wb + (size_t)kci*1024 + 512);
        }
        // additive-folded swizzle (fld from ch bits only; verified bit-level)
        int f[3];
        #pragma unroll
        for (int kw=0;kw<3;kw++){
            int s7  = ((l & SWZ) + kw) & SWZ;
            int fld = (k16*2 + hf) & SWZ;
            f[kw] = kw*CIN*2 + k16*32 + (((fld ^ s7) - fld) << 4);
        }
        #pragma unroll
        for (int tap=0; tap<9; tap++){
            const int kd = tap/3, kw = tap - kd*3;
            #pragma unroll
            for (int tr=0;tr<2;tr++){
                short8 bv = *reinterpret_cast<const short8*>(lds + kd*ROWB + tb0[tr] + f[kw]);
                acc[0][tr] = __builtin_amdgcn_mfma_f32_32x32x16_bf16(pa[tap][0], bv, acc[0][tr], 0,0,0);
                acc[1][tr] = __builtin_amdgcn_mfma_f32_32x32x16_bf16(pa[tap][1], bv, acc[1][tr], 0,0,0);
            }
        }
    }

    __syncthreads();    // compute done; lds reusable as bounce buffer

    // epilogue: C layout col=o3=cl, co = ct*32 + (r&3)+8*(r>>2)+4*hf
    float mmv[2];
    #pragma unroll
    for (int tr=0;tr<2;tr++){
        int o2r  = r0 + 2*w + tr;
        int ovox = (kind==0) ? ((o2r*ND2 + z)*ND3 + cl)
                             : ((z*ND2 + o2r)*ND3 + cl);
        mmv[tr] = mout[ovox];
    }
    #pragma unroll
    for (int ct=0;ct<2;ct++){
        float s1[16], s2[16];
        #pragma unroll
        for (int r=0;r<16;r++){ s1[r]=0.f; s2[r]=0.f; }
        #pragma unroll
        for (int tr=0;tr<2;tr++){
            int vloc = (2*w+tr)*32 + cl;
            float xv[16];
            #pragma unroll
            for (int r=0;r<16;r++){
                float v = lrelu(acc[ct][tr][r]*mmv[tr]);
                xv[r] = v; s1[r] += v; s2[r] += v*v;
            }
            #pragma unroll
            for (int rg4=0;rg4<4;rg4++){
                int cob = ct*32 + 8*rg4 + 4*hf;
                *reinterpret_cast<uint2*>(lds + vloc*OBST + cob*2) =
                    make_uint2(cvtpk(xv[rg4*4+0],xv[rg4*4+1]), cvtpk(xv[rg4*4+2],xv[rg4*4+3]));
            }
        }
        #pragma unroll
        for (int r=0;r<16;r++){
            float a = s1[r], b = s2[r];
            a += __shfl_xor(a,1);  b += __shfl_xor(b,1);
            a += __shfl_xor(a,2);  b += __shfl_xor(b,2);
            a += __shfl_xor(a,4);  b += __shfl_xor(b,4);
            a += __shfl_xor(a,8);  b += __shfl_xor(b,8);
            a += __shfl_xor(a,16); b += __shfl_xor(b,16);
            if (cl == 0){
                int co = ct*32 + (r&3) + 8*(r>>2) + 4*hf;
                atomicAdd(&sst[co], a);
                atomicAdd(&sst[64 + co], b);
            }
        }
    }
    __syncthreads();
    #pragma unroll
    for (int i=0;i<8;i++){
        int idx = i*256 + tid;
        int vloc = idx >> 3;
        int q    = idx & 7;
        int row  = vloc >> 5;
        int o3g  = vloc & 31;
        int gvox = (kind==0) ? (((r0+row)*ND2 + z)*ND3 + o3g)
                             : ((z*ND2 + (r0+row))*ND3 + o3g);
        uint4 v = *reinterpret_cast<uint4*>(lds + vloc*OBST + q*16);
        *reinterpret_cast<uint4*>(outb + (size_t)gvox*64 + q*8) = v;
    }
    if (tid < 128){
        float* sg = statsN + (size_t)(blockIdx.x & (NSC-1))*128;
        atomicAdd(&sg[tid], sst[tid]);
    }
}

// ---------------- pool conv (known-good, legacy weight layout) ----------------
__launch_bounds__(256, 2)
__global__ void mpool5(const unsigned short* __restrict__ in,
                       const unsigned short* __restrict__ Wt,
                       const float* __restrict__ mout,
                       float* __restrict__ outf)
{
    constexpr int SLOTB = 80;
    constexpr int ROWB  = 34*SLOTB;
    extern __shared__ __align__(16) char lds[];

    const int tid = threadIdx.x;
    const int w = tid>>6, l = tid&63, g = l>>4, lj = l&15;
    const int h = w&1, rg = w>>1;

    int gi = (blockIdx.x & 7)*(gridDim.x>>3) + (blockIdx.x>>3);
    int z  = gi % OD1;
    int r0 = (gi / OD1)*4;

    const int sd3 = tid>>3;
    const int kq  = tid&7;

    for (int i = tid; i < 27*2*4; i += 256){
        int row = i >> 3, rem = i & 7;
        int slot = (rem >= 4) ? 33 : 0;
        int c16 = rem & 3;
        *reinterpret_cast<uint4*>(lds + row*ROWB + slot*SLOTB + c16*16) = make_uint4(0,0,0,0);
    }

    int ovx[4];
    float om[4];
    #pragma unroll
    for (int t=0;t<4;t++){
        int row = rg*2 + (t>>1);
        int o3  = (t&1)*16 + lj;
        ovx[t] = (z*OD2 + (r0 + row))*OD3 + o3;
        om[t]  = mout[ovx[t]];
    }

    f32x4 acc[2][4];
    #pragma unroll
    for (int c=0;c<2;c++)
        #pragma unroll
        for (int t=0;t<4;t++)
            #pragma unroll
            for (int q=0;q<4;q++) acc[c][t][q] = 0.f;

    const unsigned short* wbase = Wt + (size_t)(h*32)*32 + lj*32 + g*8;

    #pragma unroll 1
    for (int ph=0; ph<2; ph++){
        uint2 v[27];
        #pragma unroll
        for (int i=0;i<27;i++){
            const int kd = i/9, rr = i - (i/9)*9;
            int d1 = 2*z - 1 + kd;
            int d2 = 2*r0 - 1 + rr;
            v[i] = make_uint2(0,0);
            if ((unsigned)d1 < (unsigned)ND1 && (unsigned)d2 < (unsigned)ND2){
                int vox = (d1*ND2 + d2)*ND3 + sd3;
                v[i] = *reinterpret_cast<const uint2*>(in + (size_t)vox*64 + ph*32 + kq*4);
            }
        }
        __syncthreads();
        #pragma unroll
        for (int i=0;i<27;i++){
            *reinterpret_cast<uint2*>(lds + i*ROWB + (sd3+1)*SLOTB + kq*8) = v[i];
        }
        __syncthreads();

        #pragma unroll
        for (int kd=0; kd<3; kd++){
            short8 pa[9][2];
            #pragma unroll
            for (int tap=0; tap<9; tap++){
                const int kc = (kd*9 + tap)*2 + ph;
                pa[tap][0] = *reinterpret_cast<const short8*>(wbase + (size_t)kc*2048);
                pa[tap][1] = *reinterpret_cast<const short8*>(wbase + (size_t)kc*2048 + 512);
            }
            #pragma unroll
            for (int tap=0; tap<9; tap++){
                const int kh = tap/3, kw = tap - (tap/3)*3;
                #pragma unroll
                for (int t=0;t<4;t++){
                    const int rr = 2*(rg*2 + (t>>1)) + kh;
                    const int slot = (t&1)*16 + lj + kw;
                    const char* bp = lds + (kd*9 + rr)*ROWB + slot*SLOTB + g*16;
                    short8 bv = *reinterpret_cast<const short8*>(bp);
                    acc[0][t] = __builtin_amdgcn_mfma_f32_16x16x32_bf16(pa[tap][0], bv, acc[0][t], 0,0,0);
                    acc[1][t] = __builtin_amdgcn_mfma_f32_16x16x32_bf16(pa[tap][1], bv, acc[1][t], 0,0,0);
                }
            }
        }
    }

    __syncthreads();
    float* olds = (float*)lds;
    #pragma unroll
    for (int c=0;c<2;c++){
        const int ct = h*2 + c;
        #pragma unroll
        for (int t=0;t<4;t++){
            int row = rg*2 + (t>>1);
            int o3  = (t&1)*16 + lj;
            #pragma unroll
            for (int r=0;r<4;r++){
                int co = ct*16 + g*4 + r;
                olds[co*128 + row*32 + o3] = acc[c][t][r]*om[t];
            }
        }
    }
    __syncthreads();
    const size_t obase = (size_t)(z*OD2 + r0)*OD3;
    #pragma unroll
    for (int i=0;i<8;i++){
        int idx = i*256 + tid;
        int co  = idx >> 5;
        int q   = idx & 31;
        uint4 v = *reinterpret_cast<uint4*>(reinterpret_cast<char*>(olds) + co*512 + q*16);
        *reinterpret_cast<uint4*>(outf + (size_t)co*OSP + obase + q*4) = v;
    }
}

// ---------------- launch ----------------
extern "C" void kernel_launch(void* const* d_in, const int* in_sizes, int n_in,
                              void* d_out, int out_size, void* d_ws, size_t ws_size,
                              hipStream_t stream)
{
    const float* x      = (const float*)d_in[0];
    const void*  mraw   = d_in[1];
    const float* W_A1   = (const float*)d_in[2];
    const float* W_A2   = (const float*)d_in[3];
    const float* W_B1   = (const float*)d_in[4];
    const float* W_B2   = (const float*)d_in[5];
    const float* W_pool = (const float*)d_in[6];
    const float* g_A1 = (const float*)d_in[7],  *b_A1 = (const float*)d_in[8];
    const float* g_A2 = (const float*)d_in[9],  *b_A2 = (const float*)d_in[10];
    const float* g_B1 = (const float*)d_in[11], *b_B1 = (const float*)d_in[12];
    const float* g_B2 = (const float*)d_in[13], *b_B2 = (const float*)d_in[14];

    char* p = (char*)d_ws;
    float* m     = (float*)p; p += (size_t)SP*4;
    float* omask = (float*)p; p += (size_t)OSP*4;
    float* statsN= (float*)p; p += 4*NSC*128*4;
    float* scsh  = (float*)p; p += 4*128*4;
    float* nactN = (float*)p; p += NSC*4;
    int*   flag  = (int*)p;   p += 4;
    p += 252;
    unsigned short* WtA1 = (unsigned short*)p; p += 288*64*2;
    unsigned short* WtA2 = (unsigned short*)p; p += 576*64*2;
    unsigned short* WtB1 = (unsigned short*)p; p += 288*64*2;
    unsigned short* WtB2 = (unsigned short*)p; p += 576*64*2;
    unsigned short* WtP  = (unsigned short*)p; p += 1728*64*2;
    unsigned short* X = (unsigned short*)p; p += (size_t)SP*32*2;
    unsigned short* P = (unsigned short*)p; p += (size_t)SP*64*2;
    unsigned short* Q = (unsigned short*)p; p += (size_t)SP*64*2;
    unsigned short* R = (unsigned short*)p; p += (size_t)SP*64*2;
    unsigned short* S = (unsigned short*)p; p += (size_t)SP*64*2;

    float* down = (float*)d_out;                 // [64][OSP]
    float* resf = down + (size_t)CO*OSP;         // [64][SP]

    const int shmP = 27*34*80;                   // 73440
    hipFuncSetAttribute((const void*)&mpool5, hipFuncAttributeMaxDynamicSharedMemorySize, shmP);

    hipMemsetAsync(statsN, 0, (4*NSC*128 + 4*128 + NSC)*4 + 4, stream);
    k_detect<<<256, 256, 0, stream>>>((const unsigned char*)mraw, flag);
    k_mask<<<SP/256, 256, 0, stream>>>(mraw, flag, m, nactN);
    k_wprep_all<<<864, 256, 0, stream>>>(W_A1, W_A2, W_B1, W_B2, W_pool,
                                         WtA1, WtA2, WtB1, WtB2, WtP);
    k_prep_x<<<SP/64, 256, 0, stream>>>(x, m, X, omask);

    float* SA1 = statsN + 0*NSC*128;
    float* SA2 = statsN + 1*NSC*128;
    float* SB1 = statsN + 2*NSC*128;
    float* SB2 = statsN + 3*NSC*128;

    // stage 1: A1 (KIND0, X->P) + B1 (KIND1, X->Q)
    mconv_dual<32,false,0,1><<<6400, 256, 0, stream>>>(
        X, WtA1, nullptr, P, SA1,
        X, WtB1, nullptr, Q, SB1, nullptr, m);
    k_finalize2<<<2, 64, 0, stream>>>(SA1, g_A1, b_A1, scsh + 0,
                                      SB1, g_B1, b_B1, scsh + 256, nactN);
    // stage 2: A2 (KIND1, P->R) + B2 (KIND0, Q->S)
    mconv_dual<64,true,1,0><<<6400, 256, 0, stream>>>(
        P, WtA2, scsh + 0,   R, SA2,
        Q, WtB2, scsh + 256, S, SB2, m, m);
    k_finalize2<<<2, 64, 0, stream>>>(SA2, g_A2, b_A2, scsh + 128,
                                      SB2, g_B2, b_B2, scsh + 384, nactN);
    // res_B combine -> Q (bf16 for pool) + resf (f32 output)
    k_resB<<<SP/64, 256, 0, stream>>>(R, S, scsh + 128, scsh + 384, m, Q, resf);
    // pool
    mpool5<<<1600, 256, shmP, stream>>>(Q, WtP, omask, down);
}

// Round 21
// 574.815 us; speedup vs baseline: 1.2450x; 1.2450x over previous
//
#include <hip/hip_runtime.h>

static constexpr int ND1=160, ND2=160, ND3=32;
static constexpr int SP  = ND1*ND2*ND3;        // 819200
static constexpr int CO  = 64;
static constexpr int OD1=80, OD2=80, OD3=32;
static constexpr int OSP = OD1*OD2*OD3;        // 204800
static constexpr int NSC = 64;

typedef __attribute__((ext_vector_type(8))) short  short8;
typedef __attribute__((ext_vector_type(4))) float  f32x4;

__device__ __forceinline__ float b2f(unsigned u){ return __uint_as_float(u<<16); }
__device__ __forceinline__ float b2f_lo(unsigned u){ return __uint_as_float(u<<16); }
__device__ __forceinline__ float b2f_hi(unsigned u){ return __uint_as_float(u & 0xffff0000u); }
__device__ __forceinline__ unsigned short f2b(float f){
    unsigned u = __float_as_uint(f);
    u += 0x7fffu + ((u>>16)&1u);
    return (unsigned short)(u>>16);
}
// packed f32x2 -> bf16x2 (RNE), 1 VALU inst
__device__ __forceinline__ unsigned cvtpk(float lo, float hi){
    unsigned r;
    asm("v_cvt_pk_bf16_f32 %0, %1, %2" : "=v"(r) : "v"(lo), "v"(hi));
    return r;
}
__device__ __forceinline__ float lrelu(float x){ return fmaxf(x, 0.01f*x); }

// ---------------- mask dtype detection ----------------
__global__ void k_detect(const unsigned char* __restrict__ mb, int* __restrict__ flag)
{
    __shared__ int lf;
    if (threadIdx.x == 0) lf = 0;
    __syncthreads();
    int f = 0;
    for (int i = blockIdx.x*256 + threadIdx.x; i < SP; i += gridDim.x*256) {
        unsigned char b = mb[i];
        if (b > 1) f |= 4;
        if (b != 0 && (i & 3)) f |= 1;
    }
    if (f) atomicOr(&lf, f);
    __syncthreads();
    if (threadIdx.x == 0 && lf) atomicOr(flag, lf);
}

__global__ void k_mask(const void* __restrict__ mraw, const int* __restrict__ flag,
                       float* __restrict__ m, float* __restrict__ nactN)
{
    int i = blockIdx.x*256 + threadIdx.x;
    int f = *flag;
    float v;
    if (f & 4)      v = (reinterpret_cast<const float*>(mraw)[i] != 0.f) ? 1.f : 0.f;
    else if (f & 1) v = (reinterpret_cast<const unsigned char*>(mraw)[i] != 0) ? 1.f : 0.f;
    else            v = (reinterpret_cast<const int*>(mraw)[i] != 0) ? 1.f : 0.f;
    m[i] = v;
    float s = v;
    #pragma unroll
    for (int off = 32; off > 0; off >>= 1) s += __shfl_xor(s, off);
    __shared__ float wsum[4];
    if ((threadIdx.x & 63) == 0) wsum[threadIdx.x >> 6] = s;
    __syncthreads();
    if (threadIdx.x == 0) atomicAdd(&nactN[blockIdx.x & (NSC-1)], wsum[0]+wsum[1]+wsum[2]+wsum[3]);
}

// ---------------- BN finalize (2 stages/launch) ----------------
__global__ void k_finalize2(const float* __restrict__ SN0, const float* __restrict__ g0,
                            const float* __restrict__ b0, float* __restrict__ o0,
                            const float* __restrict__ SN1, const float* __restrict__ g1,
                            const float* __restrict__ b1, float* __restrict__ o1,
                            const float* __restrict__ nactN)
{
    const float* SN = blockIdx.x ? SN1 : SN0;
    const float* g  = blockIdx.x ? g1  : g0;
    const float* b  = blockIdx.x ? b1  : b0;
    float*       o  = blockIdx.x ? o1  : o0;
    int c = threadIdx.x;
    float s1 = 0.f, s2 = 0.f;
    #pragma unroll 4
    for (int k = 0; k < NSC; k++){
        s1 += SN[k*128 + c];
        s2 += SN[k*128 + 64 + c];
    }
    float nn = nactN[c];
    #pragma unroll
    for (int off = 32; off > 0; off >>= 1) nn += __shfl_xor(nn, off);
    float mean = s1 / nn;
    float var  = s2 / nn - mean*mean;
    float inv  = rsqrtf(var + 1e-5f);
    float sc   = inv * g[c];
    o[c]      = sc;
    o[64 + c] = b[c] - mean*sc;
}

// ---------------- merged weight pre-pack ----------------
__global__ void k_wprep_all(const float* __restrict__ WA1, const float* __restrict__ WA2,
                            const float* __restrict__ WB1, const float* __restrict__ WB2,
                            const float* __restrict__ WP,
                            unsigned short* __restrict__ tA1, unsigned short* __restrict__ tA2,
                            unsigned short* __restrict__ tB1, unsigned short* __restrict__ tB2,
                            unsigned short* __restrict__ tP)
{
    int i = blockIdx.x*256 + threadIdx.x;
    const float* W; unsigned short* Wt; int CIN, NT, base;
    if      (i < 18432)  { W=WA1; Wt=tA1; CIN=32; NT=9;  base=0; }
    else if (i < 55296)  { W=WA2; Wt=tA2; CIN=64; NT=9;  base=18432; }
    else if (i < 73728)  { W=WB1; Wt=tB1; CIN=32; NT=9;  base=55296; }
    else if (i < 110592) { W=WB2; Wt=tB2; CIN=64; NT=9;  base=73728; }
    else if (i < 221184) { W=WP;  Wt=tP;  CIN=64; NT=27; base=110592; }
    else return;
    int j = i - base;
    int ksub = j & 31;
    int t = j >> 5;
    int co = t & 63;
    int kc = t >> 6;
    int nch = CIN >> 5;
    int tap = kc / nch;
    int ci  = (kc - tap*nch)*32 + ksub;
    Wt[j] = f2b(W[((size_t)co*CIN + ci)*NT + tap]);
}

// ---------------- x prep (+ out_mask fold) ----------------
__global__ void k_prep_x(const float* __restrict__ x, const float* __restrict__ m,
                         unsigned short* __restrict__ xt, float* __restrict__ om)
{
    __shared__ float t[64][33];
    int sp0 = blockIdx.x*64;
    int tid = threadIdx.x;
    int c = tid>>6, s = tid&63;
    float mm = m[sp0+s];
    #pragma unroll
    for (int r=0;r<8;r++){
        int ci = c + r*4;
        t[s][ci] = x[(size_t)ci*SP + sp0 + s]*mm;
    }
    __syncthreads();
    int sp = tid>>2, c0 = (tid&3)*8;
    uint4 pk;
    pk.x = cvtpk(t[sp][c0+0], t[sp][c0+1]);
    pk.y = cvtpk(t[sp][c0+2], t[sp][c0+3]);
    pk.z = cvtpk(t[sp][c0+4], t[sp][c0+5]);
    pk.w = cvtpk(t[sp][c0+6], t[sp][c0+7]);
    *reinterpret_cast<uint4*>(xt + (size_t)(sp0+sp)*32 + c0) = pk;

    if (blockIdx.x < OSP/256){
        int i = blockIdx.x*256 + tid;
        int o3 = i & 31; int tt = i >> 5; int o2 = tt % OD2; int o1 = tt / OD2;
        float ssum = 0.f;
        for (int kd = 0; kd < 3; kd++) { int d1 = 2*o1 - 1 + kd; if ((unsigned)d1 >= ND1) continue;
          for (int kh = 0; kh < 3; kh++) { int d2 = 2*o2 - 1 + kh; if ((unsigned)d2 >= ND2) continue;
            for (int kw = 0; kw < 3; kw++) { int d3 = o3 - 1 + kw; if ((unsigned)d3 >= ND3) continue;
              ssum += m[(d1*ND2 + d2)*ND3 + d3];
            } } }
        om[i] = (ssum > 0.f) ? 1.f : 0.f;
    }
}

// ---------------- res_B combine ----------------
__global__ void k_resB(const unsigned short* __restrict__ hA, const unsigned short* __restrict__ hB,
                       const float* __restrict__ sA, const float* __restrict__ sB,
                       const float* __restrict__ m,
                       unsigned short* __restrict__ rbt, float* __restrict__ resf)
{
    __shared__ float t[64][65];
    __shared__ float ss[256];
    int tid = threadIdx.x;
    if (tid < 128){ ss[tid] = sA[tid]; ss[128+tid] = sB[tid]; }
    __syncthreads();
    int sp0 = blockIdx.x*64;
    int sp = tid>>2, c0 = (tid&3)*16;
    float mm = m[sp0+sp];
    const size_t base = (size_t)(sp0+sp)*64 + c0;
    uint4 a0 = *reinterpret_cast<const uint4*>(hA + base);
    uint4 a1 = *reinterpret_cast<const uint4*>(hA + base + 8);
    uint4 b0 = *reinterpret_cast<const uint4*>(hB + base);
    uint4 b1 = *reinterpret_cast<const uint4*>(hB + base + 8);
    unsigned pa4[8] = {a0.x,a0.y,a0.z,a0.w,a1.x,a1.y,a1.z,a1.w};
    unsigned pb4[8] = {b0.x,b0.y,b0.z,b0.w,b1.x,b1.y,b1.z,b1.w};
    float vv[16];
    #pragma unroll
    for (int q=0;q<8;q++){
        int ci = c0+q*2;
        float va0 = b2f_lo(pa4[q]), va1 = b2f_hi(pa4[q]);
        float vb0 = b2f_lo(pb4[q]), vb1 = b2f_hi(pb4[q]);
        float v0 = (va0*ss[ci]   + ss[64+ci]   + vb0*ss[128+ci]   + ss[192+ci])*mm;
        float v1 = (va1*ss[ci+1] + ss[64+ci+1] + vb1*ss[128+ci+1] + ss[192+ci+1])*mm;
        t[sp][ci] = v0; t[sp][ci+1] = v1;
        vv[q*2] = v0; vv[q*2+1] = v1;
    }
    uint4 p0, p1;
    p0.x = cvtpk(vv[0],vv[1]);   p0.y = cvtpk(vv[2],vv[3]);
    p0.z = cvtpk(vv[4],vv[5]);   p0.w = cvtpk(vv[6],vv[7]);
    p1.x = cvtpk(vv[8],vv[9]);   p1.y = cvtpk(vv[10],vv[11]);
    p1.z = cvtpk(vv[12],vv[13]); p1.w = cvtpk(vv[14],vv[15]);
    *reinterpret_cast<uint4*>(rbt + base)     = p0;
    *reinterpret_cast<uint4*>(rbt + base + 8) = p1;
    __syncthreads();
    int ci = tid>>2, s0 = (tid&3)*16;
    #pragma unroll
    for (int kq=0;kq<4;kq++){
        float4 ov;
        ov.x = t[s0+4*kq+0][ci]; ov.y = t[s0+4*kq+1][ci];
        ov.z = t[s0+4*kq+2][ci]; ov.w = t[s0+4*kq+3][ci];
        *reinterpret_cast<float4*>(resf + (size_t)ci*SP + sp0 + s0 + 4*kq) = ov;
    }
}

// ---------------- dual MFMA conv: per-ch weight regs, cvt_pk epilogue, coalesced bounce ----------------
template<int CIN, bool HASAFF, int KA, int KB>
__launch_bounds__(256, 3)
__global__ void mconv_dual(const unsigned short* __restrict__ inA, const unsigned short* __restrict__ WtA,
                           const float* __restrict__ scshA, unsigned short* __restrict__ outA,
                           float* __restrict__ statsA,
                           const unsigned short* __restrict__ inB, const unsigned short* __restrict__ WtB,
                           const float* __restrict__ scshB, unsigned short* __restrict__ outB2,
                           float* __restrict__ statsB,
                           const float* __restrict__ mstage, const float* __restrict__ mout)
{
    constexpr int NCH  = CIN/32;
    constexpr int NR   = 10;
    constexpr int ROWB = 34*CIN*2;
    constexpr int SWZ  = (CIN==64) ? 7 : 3;
    constexpr int OBST = 160;                       // bounce stride (round-16 best)
    constexpr int LDSZ = (NR*ROWB > 256*OBST) ? NR*ROWB : 256*OBST;
    __shared__ __align__(16) char lds[LDSZ];
    __shared__ float sst[128];

    const int tid = threadIdx.x;
    const int w = tid>>6, l = tid&63, g = l>>4, lj = l&15;
    const int h = w&1, rg = w>>1;

    const int bid  = blockIdx.x;
    const int hb   = (bid >= 3200) ? 1 : 0;
    const int b2   = bid - hb*3200;
    const int gi   = (b2&7)*400 + (b2>>3);
    const int kind = hb ? KB : KA;
    const unsigned short* in  = hb ? inB   : inA;
    const unsigned short* Wt  = hb ? WtB   : WtA;
    const float*        scsh  = hb ? scshB : scshA;
    unsigned short*     outb  = hb ? outB2 : outA;
    float*             statsN = hb ? statsB : statsA;

    int z  = gi % 160;
    int r0 = (gi / 160)*8;

    if (tid < 128) sst[tid] = 0.f;

    const int sd3 = tid>>3;
    const int k0  = (tid&7)*(CIN/8);

    float sc[8], sh[8];
    if (HASAFF){
        #pragma unroll
        for (int j=0;j<8;j++){ sc[j]=scsh[k0+j]; sh[j]=scsh[64+k0+j]; }
    }

    // border zeros (slots 0 and 33)
    for (int i = tid; i < NR*2*(CIN/8); i += 256){
        int per = CIN/8;
        int rr = i / (2*per);
        int rem = i - rr*2*per;
        int slot = (rem >= per) ? 33 : 0;
        int kc16 = (rem >= per) ? (rem - per) : rem;
        int dst = rr*ROWB + slot*CIN*2 + kc16*16;
        dst ^= ((slot&SWZ)<<4);
        *reinterpret_cast<uint4*>(lds + dst) = make_uint4(0,0,0,0);
    }

    // stage full-CIN rows, batched, slot-XOR swizzled
    if (CIN==64){
        uint4 v[NR]; float mmr[NR];
        #pragma unroll
        for (int rr=0; rr<NR; rr++){
            int rw = r0 - 1 + rr;
            v[rr] = make_uint4(0,0,0,0); mmr[rr] = 0.f;
            if ((unsigned)rw < 160u){
                int vox = (kind==0) ? ((rw*ND2 + z)*ND3 + sd3)
                                    : ((z*ND2 + rw)*ND3 + sd3);
                v[rr] = *reinterpret_cast<const uint4*>(in + (size_t)vox*CIN + k0);
                if (HASAFF) mmr[rr] = mstage[vox];
            }
        }
        #pragma unroll
        for (int rr=0; rr<NR; rr++){
            uint4 vv = v[rr];
            if (HASAFF){
                float mm = mmr[rr];
                float q0 = (b2f_lo(vv.x)*sc[0]+sh[0])*mm;
                float q1 = (b2f_hi(vv.x)*sc[1]+sh[1])*mm;
                float q2 = (b2f_lo(vv.y)*sc[2]+sh[2])*mm;
                float q3 = (b2f_hi(vv.y)*sc[3]+sh[3])*mm;
                float q4 = (b2f_lo(vv.z)*sc[4]+sh[4])*mm;
                float q5 = (b2f_hi(vv.z)*sc[5]+sh[5])*mm;
                float q6 = (b2f_lo(vv.w)*sc[6]+sh[6])*mm;
                float q7 = (b2f_hi(vv.w)*sc[7]+sh[7])*mm;
                vv.x = cvtpk(q0,q1); vv.y = cvtpk(q2,q3);
                vv.z = cvtpk(q4,q5); vv.w = cvtpk(q6,q7);
            }
            int dst = (rr*ROWB + (((sd3+1)*CIN + k0)*2)) ^ (((sd3+1)&SWZ)<<4);
            *reinterpret_cast<uint4*>(lds + dst) = vv;
        }
    } else {
        uint2 v[NR];
        #pragma unroll
        for (int rr=0; rr<NR; rr++){
            int rw = r0 - 1 + rr;
            v[rr] = make_uint2(0,0);
            if ((unsigned)rw < 160u){
                int vox = (kind==0) ? ((rw*ND2 + z)*ND3 + sd3)
                                    : ((z*ND2 + rw)*ND3 + sd3);
                v[rr] = *reinterpret_cast<const uint2*>(in + (size_t)vox*CIN + k0);
            }
        }
        #pragma unroll
        for (int rr=0; rr<NR; rr++){
            int dst = (rr*ROWB + (((sd3+1)*CIN + k0)*2)) ^ (((sd3+1)&SWZ)<<4);
            *reinterpret_cast<uint2*>(lds + dst) = v[rr];
        }
    }

    int tb[8];
    #pragma unroll
    for (int t=0;t<8;t++){
        int rowb = rg*4 + (t>>1);
        int o3   = (t&1)*16 + lj;
        tb[t] = rowb*ROWB + ((o3*CIN + g*8)*2);
    }
    int swz[3];
    #pragma unroll
    for (int kw=0;kw<3;kw++) swz[kw] = ((lj+kw)&SWZ)<<4;

    __syncthreads();

    f32x4 acc[2][8];
    #pragma unroll
    for (int c=0;c<2;c++)
        #pragma unroll
        for (int t=0;t<8;t++)
            #pragma unroll
            for (int q=0;q<4;q++) acc[c][t][q] = 0.f;

    const unsigned short* wb = Wt + (size_t)(h*32)*32 + lj*32 + g*8;

    #pragma unroll 1
    for (int ch=0; ch<NCH; ch++){
        short8 pa[9][2];
        #pragma unroll
        for (int tap=0; tap<9; tap++){
            const int kc = tap*NCH + ch;
            pa[tap][0] = *reinterpret_cast<const short8*>(wb + (size_t)kc*2048);
            pa[tap][1] = *reinterpret_cast<const short8*>(wb + (size_t)kc*2048 + 512);
        }
        #pragma unroll
        for (int tap=0; tap<9; tap++){
            const int kd = tap/3, kw = tap - kd*3;
            const int tapoff = kd*ROWB + (kw*CIN + ch*32)*2;
            #pragma unroll
            for (int t=0;t<8;t++){
                int off = (tb[t] + tapoff) ^ swz[kw];
                short8 bv = *reinterpret_cast<const short8*>(lds + off);
                acc[0][t] = __builtin_amdgcn_mfma_f32_16x16x32_bf16(pa[tap][0], bv, acc[0][t], 0,0,0);
                acc[1][t] = __builtin_amdgcn_mfma_f32_16x16x32_bf16(pa[tap][1], bv, acc[1][t], 0,0,0);
            }
        }
    }

    __syncthreads();    // compute done; lds reusable as bounce buffer

    float mmv[8];
    #pragma unroll
    for (int t=0;t<8;t++){
        int rowb = rg*4 + (t>>1);
        int o3   = (t&1)*16 + lj;
        int o2r  = r0 + rowb;
        int ovox = (kind==0) ? ((o2r*ND2 + z)*ND3 + o3)
                             : ((z*ND2 + o2r)*ND3 + o3);
        mmv[t] = mout[ovox];
    }
    #pragma unroll
    for (int c=0;c<2;c++){
        const int ct = h*2 + c;
        float s1[4] = {0.f,0.f,0.f,0.f};
        float s2[4] = {0.f,0.f,0.f,0.f};
        #pragma unroll
        for (int t=0;t<8;t++){
            int rowb = rg*4 + (t>>1);
            int o3   = (t&1)*16 + lj;
            int vloc = rowb*32 + o3;
            float v[4];
            #pragma unroll
            for (int r=0;r<4;r++){
                float xv = lrelu(acc[c][t][r]*mmv[t]);
                v[r] = xv; s1[r] += xv; s2[r] += xv*xv;
            }
            *reinterpret_cast<uint2*>(lds + vloc*OBST + (ct*16 + g*4)*2) =
                make_uint2(cvtpk(v[0],v[1]), cvtpk(v[2],v[3]));
        }
        #pragma unroll
        for (int r=0;r<4;r++){
            float a = s1[r], b = s2[r];
            a += __shfl_xor(a,1); b += __shfl_xor(b,1);
            a += __shfl_xor(a,2); b += __shfl_xor(b,2);
            a += __shfl_xor(a,4); b += __shfl_xor(b,4);
            a += __shfl_xor(a,8); b += __shfl_xor(b,8);
            if (lj == 0){
                atomicAdd(&sst[ct*16 + g*4 + r], a);
                atomicAdd(&sst[64 + ct*16 + g*4 + r], b);
            }
        }
    }
    __syncthreads();
    #pragma unroll
    for (int i=0;i<8;i++){
        int idx = i*256 + tid;
        int vloc = idx >> 3;
        int q    = idx & 7;
        int row  = vloc >> 5;
        int o3g  = vloc & 31;
        int gvox = (kind==0) ? (((r0+row)*ND2 + z)*ND3 + o3g)
                             : ((z*ND2 + (r0+row))*ND3 + o3g);
        uint4 v = *reinterpret_cast<uint4*>(lds + vloc*OBST + q*16);
        *reinterpret_cast<uint4*>(outb + (size_t)gvox*64 + q*8) = v;
    }
    if (tid < 128){
        float* sg = statsN + (size_t)(blockIdx.x & (NSC-1))*128;
        atomicAdd(&sg[tid], sst[tid]);
    }
}

// ---------------- pool conv (known-good) ----------------
__launch_bounds__(256, 2)
__global__ void mpool5(const unsigned short* __restrict__ in,
                       const unsigned short* __restrict__ Wt,
                       const float* __restrict__ mout,
                       float* __restrict__ outf)
{
    constexpr int SLOTB = 80;
    constexpr int ROWB  = 34*SLOTB;
    extern __shared__ __align__(16) char lds[];

    const int tid = threadIdx.x;
    const int w = tid>>6, l = tid&63, g = l>>4, lj = l&15;
    const int h = w&1, rg = w>>1;

    int gi = (blockIdx.x & 7)*(gridDim.x>>3) + (blockIdx.x>>3);
    int z  = gi % OD1;
    int r0 = (gi / OD1)*4;

    const int sd3 = tid>>3;
    const int kq  = tid&7;

    for (int i = tid; i < 27*2*4; i += 256){
        int row = i >> 3, rem = i & 7;
        int slot = (rem >= 4) ? 33 : 0;
        int c16 = rem & 3;
        *reinterpret_cast<uint4*>(lds + row*ROWB + slot*SLOTB + c16*16) = make_uint4(0,0,0,0);
    }

    int ovx[4];
    float om[4];
    #pragma unroll
    for (int t=0;t<4;t++){
        int row = rg*2 + (t>>1);
        int o3  = (t&1)*16 + lj;
        ovx[t] = (z*OD2 + (r0 + row))*OD3 + o3;
        om[t]  = mout[ovx[t]];
    }

    f32x4 acc[2][4];
    #pragma unroll
    for (int c=0;c<2;c++)
        #pragma unroll
        for (int t=0;t<4;t++)
            #pragma unroll
            for (int q=0;q<4;q++) acc[c][t][q] = 0.f;

    const unsigned short* wbase = Wt + (size_t)(h*32)*32 + lj*32 + g*8;

    #pragma unroll 1
    for (int ph=0; ph<2; ph++){
        uint2 v[27];
        #pragma unroll
        for (int i=0;i<27;i++){
            const int kd = i/9, rr = i - (i/9)*9;
            int d1 = 2*z - 1 + kd;
            int d2 = 2*r0 - 1 + rr;
            v[i] = make_uint2(0,0);
            if ((unsigned)d1 < (unsigned)ND1 && (unsigned)d2 < (unsigned)ND2){
                int vox = (d1*ND2 + d2)*ND3 + sd3;
                v[i] = *reinterpret_cast<const uint2*>(in + (size_t)vox*64 + ph*32 + kq*4);
            }
        }
        __syncthreads();
        #pragma unroll
        for (int i=0;i<27;i++){
            *reinterpret_cast<uint2*>(lds + i*ROWB + (sd3+1)*SLOTB + kq*8) = v[i];
        }
        __syncthreads();

        #pragma unroll
        for (int kd=0; kd<3; kd++){
            short8 pa[9][2];
            #pragma unroll
            for (int tap=0; tap<9; tap++){
                const int kc = (kd*9 + tap)*2 + ph;
                pa[tap][0] = *reinterpret_cast<const short8*>(wbase + (size_t)kc*2048);
                pa[tap][1] = *reinterpret_cast<const short8*>(wbase + (size_t)kc*2048 + 512);
            }
            #pragma unroll
            for (int tap=0; tap<9; tap++){
                const int kh = tap/3, kw = tap - (tap/3)*3;
                #pragma unroll
                for (int t=0;t<4;t++){
                    const int rr = 2*(rg*2 + (t>>1)) + kh;
                    const int slot = (t&1)*16 + lj + kw;
                    const char* bp = lds + (kd*9 + rr)*ROWB + slot*SLOTB + g*16;
                    short8 bv = *reinterpret_cast<const short8*>(bp);
                    acc[0][t] = __builtin_amdgcn_mfma_f32_16x16x32_bf16(pa[tap][0], bv, acc[0][t], 0,0,0);
                    acc[1][t] = __builtin_amdgcn_mfma_f32_16x16x32_bf16(pa[tap][1], bv, acc[1][t], 0,0,0);
                }
            }
        }
    }

    __syncthreads();
    float* olds = (float*)lds;
    #pragma unroll
    for (int c=0;c<2;c++){
        const int ct = h*2 + c;
        #pragma unroll
        for (int t=0;t<4;t++){
            int row = rg*2 + (t>>1);
            int o3  = (t&1)*16 + lj;
            #pragma unroll
            for (int r=0;r<4;r++){
                int co = ct*16 + g*4 + r;
                olds[co*128 + row*32 + o3] = acc[c][t][r]*om[t];
            }
        }
    }
    __syncthreads();
    const size_t obase = (size_t)(z*OD2 + r0)*OD3;
    #pragma unroll
    for (int i=0;i<8;i++){
        int idx = i*256 + tid;
        int co  = idx >> 5;
        int q   = idx & 31;
        uint4 v = *reinterpret_cast<uint4*>(reinterpret_cast<char*>(olds) + co*512 + q*16);
        *reinterpret_cast<uint4*>(outf + (size_t)co*OSP + obase + q*4) = v;
    }
}

// ---------------- launch ----------------
extern "C" void kernel_launch(void* const* d_in, const int* in_sizes, int n_in,
                              void* d_out, int out_size, void* d_ws, size_t ws_size,
                              hipStream_t stream)
{
    const float* x      = (const float*)d_in[0];
    const void*  mraw   = d_in[1];
    const float* W_A1   = (const float*)d_in[2];
    const float* W_A2   = (const float*)d_in[3];
    const float* W_B1   = (const float*)d_in[4];
    const float* W_B2   = (const float*)d_in[5];
    const float* W_pool = (const float*)d_in[6];
    const float* g_A1 = (const float*)d_in[7],  *b_A1 = (const float*)d_in[8];
    const float* g_A2 = (const float*)d_in[9],  *b_A2 = (const float*)d_in[10];
    const float* g_B1 = (const float*)d_in[11], *b_B1 = (const float*)d_in[12];
    const float* g_B2 = (const float*)d_in[13], *b_B2 = (const float*)d_in[14];

    char* p = (char*)d_ws;
    float* m     = (float*)p; p += (size_t)SP*4;
    float* omask = (float*)p; p += (size_t)OSP*4;
    float* statsN= (float*)p; p += 4*NSC*128*4;
    float* scsh  = (float*)p; p += 4*128*4;
    float* nactN = (float*)p; p += NSC*4;
    int*   flag  = (int*)p;   p += 4;
    p += 252;
    unsigned short* WtA1 = (unsigned short*)p; p += 288*64*2;
    unsigned short* WtA2 = (unsigned short*)p; p += 576*64*2;
    unsigned short* WtB1 = (unsigned short*)p; p += 288*64*2;
    unsigned short* WtB2 = (unsigned short*)p; p += 576*64*2;
    unsigned short* WtP  = (unsigned short*)p; p += 1728*64*2;
    unsigned short* X = (unsigned short*)p; p += (size_t)SP*32*2;
    unsigned short* P = (unsigned short*)p; p += (size_t)SP*64*2;
    unsigned short* Q = (unsigned short*)p; p += (size_t)SP*64*2;
    unsigned short* R = (unsigned short*)p; p += (size_t)SP*64*2;
    unsigned short* S = (unsigned short*)p; p += (size_t)SP*64*2;

    float* down = (float*)d_out;                 // [64][OSP]
    float* resf = down + (size_t)CO*OSP;         // [64][SP]

    const int shmP = 27*34*80;                   // 73440
    hipFuncSetAttribute((const void*)&mpool5, hipFuncAttributeMaxDynamicSharedMemorySize, shmP);

    hipMemsetAsync(statsN, 0, (4*NSC*128 + 4*128 + NSC)*4 + 4, stream);
    k_detect<<<256, 256, 0, stream>>>((const unsigned char*)mraw, flag);
    k_mask<<<SP/256, 256, 0, stream>>>(mraw, flag, m, nactN);
    k_wprep_all<<<864, 256, 0, stream>>>(W_A1, W_A2, W_B1, W_B2, W_pool,
                                         WtA1, WtA2, WtB1, WtB2, WtP);
    k_prep_x<<<SP/64, 256, 0, stream>>>(x, m, X, omask);

    float* SA1 = statsN + 0*NSC*128;
    float* SA2 = statsN + 1*NSC*128;
    float* SB1 = statsN + 2*NSC*128;
    float* SB2 = statsN + 3*NSC*128;

    // stage 1: A1 (KIND0, X->P) + B1 (KIND1, X->Q)
    mconv_dual<32,false,0,1><<<6400, 256, 0, stream>>>(
        X, WtA1, nullptr, P, SA1,
        X, WtB1, nullptr, Q, SB1, nullptr, m);
    k_finalize2<<<2, 64, 0, stream>>>(SA1, g_A1, b_A1, scsh + 0,
                                      SB1, g_B1, b_B1, scsh + 256, nactN);
    // stage 2: A2 (KIND1, P->R) + B2 (KIND0, Q->S)
    mconv_dual<64,true,1,0><<<6400, 256, 0, stream>>>(
        P, WtA2, scsh + 0,   R, SA2,
        Q, WtB2, scsh + 256, S, SB2, m, m);
    k_finalize2<<<2, 64, 0, stream>>>(SA2, g_A2, b_A2, scsh + 128,
                                      SB2, g_B2, b_B2, scsh + 384, nactN);
    // res_B combine -> Q (bf16 for pool) + resf (f32 output)
    k_resB<<<SP/64, 256, 0, stream>>>(R, S, scsh + 128, scsh + 384, m, Q, resf);
    // pool
    mpool5<<<1600, 256, shmP, stream>>>(Q, WtP, omask, down);
}